// Round 6
// baseline (1175.176 us; speedup 1.0000x reference)
//
#include <hip/hip_runtime.h>
#include <hip/hip_bf16.h>
#include <math.h>

#define D 256

typedef short v8s __attribute__((ext_vector_type(8)));
typedef float f32x4 __attribute__((ext_vector_type(4)));
typedef float f32x16 __attribute__((ext_vector_type(16)));

__device__ __forceinline__ unsigned short f2b(float f) {
    return __bfloat16_as_ushort(__float2bfloat16(f));
}

// ---------------- prep: segstart + wconv(Wf,32x32) + wconv(Wt,16x16) -------
__global__ void prep_kernel(const int* __restrict__ batch, int* __restrict__ seg_start,
                            const float* __restrict__ Wf, unsigned short* __restrict__ Wb32,
                            const float* __restrict__ Wt, unsigned short* __restrict__ Wtb,
                            int N, int B) {
    const int blk = blockIdx.x, tid = threadIdx.x;
    if (blk < 40) {
        int b = blk * 256 + tid;
        if (b > B) return;
        int lo = 0, hi = N;
        while (lo < hi) {
            int mid = (lo + hi) >> 1;
            if (batch[mid] < b) lo = mid + 1; else hi = mid;
        }
        seg_start[b] = lo;
    } else if (blk < 296) {
        // W_feat -> 32x32x16 B-frag: B[k][n]: lane=((k>>3)&1)*32+(n&31), j=k&7
        int idx = (blk - 40) * 256 + tid;         // 65536
        int k = idx >> 8, n = idx & 255;
        int lane = ((k >> 3) & 1) * 32 + (n & 31);
        int j = k & 7, kst = k >> 4, ntile = n >> 5;
        Wb32[(((ntile * 16 + kst) * 64) + lane) * 8 + j] = f2b(Wf[k * 256 + n]);
    } else {
        // W_t -> 16x16x32 B-frag (K=512): lane=((k>>3)&3)*16+(n&15), j=k&7
        int idx = (blk - 296) * 256 + tid;        // 131072
        int k = idx >> 8, n = idx & 255;
        int ntile = n >> 4, kst = k >> 5;
        int lane = ((k >> 3) & 3) * 16 + (n & 15);
        int j = k & 7;
        Wtb[(((ntile * 16 + kst) * 64) + lane) * 8 + j] = f2b(Wt[k * 256 + n]);
    }
}

// ---------------- fused: per-graph gate + online softmax + feat GEMM + segsum
// One block per graph. Chunks of 64 nodes; 2 row-tiles x (per wave) 2 col-tiles
// of 32x32x16 MFMA. Gate accumulated from the same fp32 loads (wave 0 only).
// Online-softmax rescaling across chunks; alpha applied fp32 in epilogue.
__global__ __launch_bounds__(256, 3) void fused_graph_kernel(
    const float* __restrict__ x, const float* __restrict__ Wg,
    const float* __restrict__ bg, const unsigned short* __restrict__ Wb32,
    const float* __restrict__ bfeat, const int* __restrict__ seg_start,
    float* __restrict__ xg, int N) {

    const int b = blockIdx.x;
    const int s0 = seg_start[b];
    const int S  = seg_start[b + 1] - s0;

    const int tid = threadIdx.x;
    const int w = tid >> 6, lane = tid & 63;
    const int l31 = lane & 31, lh = lane >> 5;

    __shared__ float alpha_s[64];
    __shared__ float shr[2];          // {scale, s_chunk}

    const float bgv = bg[0];
    const float bias0 = bfeat[(w * 2 + 0) * 32 + l31];
    const float bias1 = bfeat[(w * 2 + 1) * 32 + l31];

    float m_run = -INFINITY;          // tracked by wave 0 only (valid there)
    float s_run = 0.f;
    float xg_col0 = 0.f, xg_col1 = 0.f;

    for (int c0 = 0; c0 < S; c0 += 64) {
        const int cnt = min(64, S - c0);

        // row base addresses for this chunk (pad rows clamped to last valid)
        size_t abase[2];
        #pragma unroll
        for (int rt = 0; rt < 2; rt++) {
            int i = rt * 32 + l31;
            if (i > cnt - 1) i = cnt - 1;
            abase[rt] = (size_t)(s0 + c0 + i) * D + lh * 8;
        }

        f32x16 acc[2][2];
        #pragma unroll
        for (int i = 0; i < 2; i++)
            #pragma unroll
            for (int j = 0; j < 2; j++)
                #pragma unroll
                for (int e = 0; e < 16; e++) acc[i][j][e] = 0.f;

        float gp0 = 0.f, gp1 = 0.f;   // gate partials (wave 0)

        #pragma unroll
        for (int ks = 0; ks < 16; ks++) {
            // A loads (same rows for all waves -> L1-shared), fp32 -> bf16
            float4 f00 = *(const float4*)(x + abase[0] + ks * 16);
            float4 f01 = *(const float4*)(x + abase[0] + ks * 16 + 4);
            float4 f10 = *(const float4*)(x + abase[1] + ks * 16);
            float4 f11 = *(const float4*)(x + abase[1] + ks * 16 + 4);
            v8s a0, a1;
            a0[0]=(short)f2b(f00.x); a0[1]=(short)f2b(f00.y);
            a0[2]=(short)f2b(f00.z); a0[3]=(short)f2b(f00.w);
            a0[4]=(short)f2b(f01.x); a0[5]=(short)f2b(f01.y);
            a0[6]=(short)f2b(f01.z); a0[7]=(short)f2b(f01.w);
            a1[0]=(short)f2b(f10.x); a1[1]=(short)f2b(f10.y);
            a1[2]=(short)f2b(f10.z); a1[3]=(short)f2b(f10.w);
            a1[4]=(short)f2b(f11.x); a1[5]=(short)f2b(f11.y);
            a1[6]=(short)f2b(f11.z); a1[7]=(short)f2b(f11.w);

            if (w == 0) {             // gate partials from the same fp32 data
                float4 wg0 = *(const float4*)(Wg + ks * 16 + lh * 8);
                float4 wg1 = *(const float4*)(Wg + ks * 16 + lh * 8 + 4);
                gp0 = fmaf(f00.x, wg0.x, gp0); gp0 = fmaf(f00.y, wg0.y, gp0);
                gp0 = fmaf(f00.z, wg0.z, gp0); gp0 = fmaf(f00.w, wg0.w, gp0);
                gp0 = fmaf(f01.x, wg1.x, gp0); gp0 = fmaf(f01.y, wg1.y, gp0);
                gp0 = fmaf(f01.z, wg1.z, gp0); gp0 = fmaf(f01.w, wg1.w, gp0);
                gp1 = fmaf(f10.x, wg0.x, gp1); gp1 = fmaf(f10.y, wg0.y, gp1);
                gp1 = fmaf(f10.z, wg0.z, gp1); gp1 = fmaf(f10.w, wg0.w, gp1);
                gp1 = fmaf(f11.x, wg1.x, gp1); gp1 = fmaf(f11.y, wg1.y, gp1);
                gp1 = fmaf(f11.z, wg1.z, gp1); gp1 = fmaf(f11.w, wg1.w, gp1);
            }

            v8s bf0 = *(const v8s*)(Wb32 + (((size_t)(w * 2 + 0) * 16 + ks) * 64 + lane) * 8);
            v8s bf1 = *(const v8s*)(Wb32 + (((size_t)(w * 2 + 1) * 16 + ks) * 64 + lane) * 8);

            acc[0][0] = __builtin_amdgcn_mfma_f32_32x32x16_bf16(a0, bf0, acc[0][0], 0, 0, 0);
            acc[0][1] = __builtin_amdgcn_mfma_f32_32x32x16_bf16(a0, bf1, acc[0][1], 0, 0, 0);
            acc[1][0] = __builtin_amdgcn_mfma_f32_32x32x16_bf16(a1, bf0, acc[1][0], 0, 0, 0);
            acc[1][1] = __builtin_amdgcn_mfma_f32_32x32x16_bf16(a1, bf1, acc[1][1], 0, 0, 0);
        }

        // ---- wave 0: finish gate, chunk softmax, publish alpha/scale ----
        if (w == 0) {
            gp0 += __shfl_xor(gp0, 32, 64);       // combine lh halves
            gp1 += __shfl_xor(gp1, 32, 64);
            float g0 = (l31 < cnt)      ? gp0 + bgv : -INFINITY;
            float g1 = (32 + l31 < cnt) ? gp1 + bgv : -INFINITY;
            float mm = fmaxf(g0, g1);
            #pragma unroll
            for (int off = 16; off; off >>= 1) mm = fmaxf(mm, __shfl_xor(mm, off, 64));
            float m_new = fmaxf(m_run, mm);
            float scale = __expf(m_run - m_new);
            m_run = m_new;
            float a0 = __expf(g0 - m_new);
            float a1 = __expf(g1 - m_new);
            float sc = a0 + a1;
            #pragma unroll
            for (int off = 16; off; off >>= 1) sc += __shfl_xor(sc, off, 64);
            if (lh == 0) { alpha_s[l31] = a0; alpha_s[32 + l31] = a1; }
            if (lane == 0) { shr[0] = scale; shr[1] = sc; }
        }
        __syncthreads();

        const float scale = shr[0];
        const float s_chunk = shr[1];
        s_run = s_run * scale + s_chunk;
        xg_col0 *= scale;
        xg_col1 *= scale;

        // ---- epilogue: bias + leaky + alpha (fp32), accumulate per-col ----
        // C/D 32x32: col=lane&31, row=(reg&3)+8*(reg>>2)+4*lh
        #pragma unroll
        for (int rt = 0; rt < 2; rt++) {
            #pragma unroll
            for (int g = 0; g < 4; g++) {
                #pragma unroll
                for (int rr = 0; rr < 4; rr++) {
                    float al = alpha_s[rt * 32 + rr + 8 * g + 4 * lh];
                    float y0 = acc[rt][0][g * 4 + rr] + bias0;
                    y0 = (y0 >= 0.f) ? y0 : 0.01f * y0;
                    xg_col0 = fmaf(al, y0, xg_col0);
                    float y1 = acc[rt][1][g * 4 + rr] + bias1;
                    y1 = (y1 >= 0.f) ? y1 : 0.01f * y1;
                    xg_col1 = fmaf(al, y1, xg_col1);
                }
            }
        }
        __syncthreads();   // protect alpha_s/shr before next chunk overwrites
    }

    // combine the two lh halves (each covered 32 of the 64 rows) and store
    xg_col0 += __shfl_xor(xg_col0, 32, 64);
    xg_col1 += __shfl_xor(xg_col1, 32, 64);
    const float inv = (s_run > 0.f) ? 1.f / s_run : 0.f;
    if (lh == 0) {
        xg[(size_t)b * D + (w * 2 + 0) * 32 + l31] = xg_col0 * inv;
        xg[(size_t)b * D + (w * 2 + 1) * 32 + l31] = xg_col1 * inv;
    }
}

// ---------------- K3 (MFMA, fused cat conversion) --------------------------
__global__ __launch_bounds__(256) void out_mfma_kernel(
    const float* __restrict__ xg, const float* __restrict__ xg_old,
    const unsigned short* __restrict__ Wtb, const float* __restrict__ bt,
    float* __restrict__ out, int B) {
    const int tid = threadIdx.x;
    const int w = tid >> 6, lane = tid & 63, mrow = lane & 15, q = lane >> 4;
    const int r0 = blockIdx.x * 64;

    f32x4 acc[4][4];
    #pragma unroll
    for (int i = 0; i < 4; i++)
        #pragma unroll
        for (int j = 0; j < 4; j++) acc[i][j] = (f32x4){0.f, 0.f, 0.f, 0.f};

    size_t rowbase[4];
    #pragma unroll
    for (int rb = 0; rb < 4; rb++) {
        int r = r0 + rb * 16 + mrow;
        if (r > B - 1) r = B - 1;
        rowbase[rb] = (size_t)r * D + q * 8;
    }

    #pragma unroll
    for (int ks = 0; ks < 16; ks++) {
        v8s a[4], bfr[4];
        #pragma unroll
        for (int rb = 0; rb < 4; rb++) {
            const float* src = (ks < 8) ? (xg + rowbase[rb] + ks * 32)
                                        : (xg_old + rowbase[rb] + (ks - 8) * 32);
            float4 f0 = *(const float4*)src;
            float4 f1 = *(const float4*)(src + 4);
            v8s v;
            v[0] = (short)f2b(f0.x); v[1] = (short)f2b(f0.y);
            v[2] = (short)f2b(f0.z); v[3] = (short)f2b(f0.w);
            v[4] = (short)f2b(f1.x); v[5] = (short)f2b(f1.y);
            v[6] = (short)f2b(f1.z); v[7] = (short)f2b(f1.w);
            a[rb] = v;
        }
        #pragma unroll
        for (int cb = 0; cb < 4; cb++)
            bfr[cb] = *(const v8s*)(Wtb + (((size_t)(w * 4 + cb) * 16 + ks) * 64 + lane) * 8);
        #pragma unroll
        for (int rb = 0; rb < 4; rb++)
            #pragma unroll
            for (int cb = 0; cb < 4; cb++)
                acc[rb][cb] = __builtin_amdgcn_mfma_f32_16x16x32_bf16(
                    a[rb], bfr[cb], acc[rb][cb], 0, 0, 0);
    }

    #pragma unroll
    for (int cb = 0; cb < 4; cb++) {
        int col = w * 64 + cb * 16 + mrow;
        float bias = bt[col];
        #pragma unroll
        for (int rb = 0; rb < 4; rb++) {
            #pragma unroll
            for (int reg = 0; reg < 4; reg++) {
                int row = r0 + rb * 16 + q * 4 + reg;
                if (row < B) {
                    float y = acc[rb][cb][reg] + bias;
                    y = (y >= 0.f) ? y : 0.01f * y;
                    out[(size_t)row * D + col] = y + xg_old[(size_t)row * D + col];
                }
            }
        }
    }
}

// ---------------------------------------------------------------------------
extern "C" void kernel_launch(void* const* d_in, const int* in_sizes, int n_in,
                              void* d_out, int out_size, void* d_ws, size_t ws_size,
                              hipStream_t stream) {
    const float* xg_old = (const float*)d_in[0];   // [B, D]
    const float* x      = (const float*)d_in[1];   // [N, D]
    const int*   batch  = (const int*)d_in[2];     // [N], sorted
    const float* W_gate = (const float*)d_in[3];   // [D]
    const float* b_gate = (const float*)d_in[4];   // [1]
    const float* W_feat = (const float*)d_in[5];   // [D, D]
    const float* b_feat = (const float*)d_in[6];   // [D]
    const float* W_t    = (const float*)d_in[7];   // [2D, D]
    const float* b_t    = (const float*)d_in[8];   // [D]
    float* out = (float*)d_out;                    // [B, D]

    const int N = in_sizes[1] / D;                 // 500000
    const int B = in_sizes[0] / D;                 // 10000

    // workspace layout (~10.7 MB used)
    char* ws = (char*)d_ws;
    int*            seg_start = (int*)ws;                         // 40 KB
    unsigned short* Wb32      = (unsigned short*)(ws + 0x10000);  // 128 KB
    unsigned short* Wtb       = (unsigned short*)(ws + 0x30000);  // 256 KB
    float*          xg        = (float*)(ws + 0x70000);           // 10.24 MB

    prep_kernel<<<808, 256, 0, stream>>>(batch, seg_start, W_feat, Wb32, W_t, Wtb, N, B);
    fused_graph_kernel<<<B, 256, 0, stream>>>(x, W_gate, b_gate, Wb32, b_feat,
                                              seg_start, xg, N);
    out_mfma_kernel<<<(B + 63) / 64, 256, 0, stream>>>(xg, xg_old, Wtb, b_t, out, B);
}